// Round 1
// baseline (174.605 us; speedup 1.0000x reference)
//
#include <hip/hip_runtime.h>

typedef __attribute__((ext_vector_type(4))) float f32x4;
typedef __attribute__((ext_vector_type(8))) short s16x8;
typedef unsigned short u16;

#define DEVI __device__ __forceinline__

// fp32 -> bf16 round-to-nearest-even
DEVI u16 f2bf(float f) {
    union { float f; unsigned int u; } v; v.f = f;
    unsigned int r = v.u + 0x7FFFu + ((v.u >> 16) & 1u);
    return (u16)(r >> 16);
}

typedef __attribute__((address_space(1))) void gv_t;   // global
typedef __attribute__((address_space(3))) void sv_t;   // LDS

#define GLOAD16(SRC, DST) __builtin_amdgcn_global_load_lds( \
    (gv_t*)(SRC), (sv_t*)(DST), 16, 0, 0)

DEVI f32x4 mfma_bf16(s16x8 a, s16x8 b, f32x4 c) {
    return __builtin_amdgcn_mfma_f32_16x16x32_bf16(a, b, c, 0, 0, 0);
}

// ---------------------------------------------------------------------------
// fp32 -> bf16 conversion of x, wq, wk, wv, wo (one fused streaming pass)
// region boundaries in 4-float units
// ---------------------------------------------------------------------------
__global__ void cvt_all_kernel(
    const float* __restrict__ x,  const float* __restrict__ wq, const float* __restrict__ wk,
    const float* __restrict__ wv, const float* __restrict__ wo,
    u16* __restrict__ xb, u16* __restrict__ wqb, u16* __restrict__ wkb,
    u16* __restrict__ wvb, u16* __restrict__ wob)
{
    int id = blockIdx.x * 256 + threadIdx.x;   // 0 .. 7372800-1
    const float* s; u16* d; int off;
    if      (id < 737280)  { s = x;  d = xb;  off = id; }
    else if (id < 3686400) { s = wq; d = wqb; off = id - 737280; }
    else if (id < 4055040) { s = wk; d = wkb; off = id - 3686400; }
    else if (id < 4423680) { s = wv; d = wvb; off = id - 4055040; }
    else                   { s = wo; d = wob; off = id - 4423680; }
    f32x4 v = *(const f32x4*)(s + (size_t)off * 4);
    union { u16 u[4]; unsigned long long ll; } o;
    #pragma unroll
    for (int j = 0; j < 4; ++j) o.u[j] = f2bf(v[j]);
    *(unsigned long long*)(d + (size_t)off * 4) = o.ll;
}

// ---------------------------------------------------------------------------
// NT GEMM: C[M][*] = A[M][K](bf16) * W[n][K](bf16)^T + bias, fp32 out.
// 128x128 tile, BK=64, 4 waves of 64x64, 16x16x32 bf16 MFMA.
// global_load_lds staging, XOR chunk swizzle (chunk = 16B = 8 bf16).
// Up to 3 weight regions (fused QKV); region cols clamped for ragged N.
// ---------------------------------------------------------------------------
__global__ __launch_bounds__(256, 2) void gemm_bf16nt(
    const u16* __restrict__ A, int lda, int K,
    const u16* __restrict__ W0, const float* __restrict__ b0, int t0, int n0, int c0,
    const u16* __restrict__ W1, const float* __restrict__ b1, int t1, int n1, int c1,
    const u16* __restrict__ W2, const float* __restrict__ b2, int t2, int n2, int c2,
    float* __restrict__ C, int ldc)
{
    __shared__ u16 Als[128 * 64];
    __shared__ u16 Bls[128 * 64];

    const int tid  = threadIdx.x;
    const int lane = tid & 63;
    const int wid  = tid >> 6;
    const int li   = lane & 15;
    const int lg   = lane >> 4;
    const int m0   = blockIdx.y * 128;

    const u16* W; const float* bias; int nt0, nsz, cb;
    {
        int nb = blockIdx.x;
        if (nb < t0)           { W = W0; bias = b0; nt0 = nb * 128;             nsz = n0; cb = c0; }
        else if (nb < t0 + t1) { W = W1; bias = b1; nt0 = (nb - t0) * 128;      nsz = n1; cb = c1; }
        else                   { W = W2; bias = b2; nt0 = (nb - t0 - t1) * 128; nsz = n2; cb = c2; }
    }

    const int wm = (wid >> 1) * 64;
    const int wn = (wid & 1) * 64;

    f32x4 acc[4][4];
    #pragma unroll
    for (int mi = 0; mi < 4; ++mi)
        #pragma unroll
        for (int ni = 0; ni < 4; ++ni)
            acc[mi][ni] = (f32x4){0.f, 0.f, 0.f, 0.f};

    const int srow = tid >> 3;                 // 0..31 (row within 32-row slab)
    const int slc  = (tid & 7) ^ (srow & 7);   // inverse-swizzled source chunk

    for (int k0 = 0; k0 < K; k0 += 64) {
        #pragma unroll
        for (int it = 0; it < 4; ++it) {
            const u16* sa = A + (size_t)(m0 + it * 32 + srow) * lda + k0 + slc * 8;
            GLOAD16(sa, Als + (it * 256 + wid * 64) * 8);
        }
        #pragma unroll
        for (int it = 0; it < 4; ++it) {
            int wr = nt0 + it * 32 + srow;
            if (wr > nsz - 1) wr = nsz - 1;    // ragged-N clamp (load-safe; store guarded)
            const u16* sb = W + (size_t)wr * K + k0 + slc * 8;
            GLOAD16(sb, Bls + (it * 256 + wid * 64) * 8);
        }
        __syncthreads();

        s16x8 af[4][2], bfv[4][2];
        #pragma unroll
        for (int mi = 0; mi < 4; ++mi)
            #pragma unroll
            for (int kc = 0; kc < 2; ++kc) {
                int row = wm + mi * 16 + li;
                int ch  = (kc * 4 + lg) ^ (row & 7);
                af[mi][kc] = *(const s16x8*)&Als[row * 64 + ch * 8];
            }
        #pragma unroll
        for (int ni = 0; ni < 4; ++ni)
            #pragma unroll
            for (int kc = 0; kc < 2; ++kc) {
                int row = wn + ni * 16 + li;
                int ch  = (kc * 4 + lg) ^ (row & 7);
                bfv[ni][kc] = *(const s16x8*)&Bls[row * 64 + ch * 8];
            }
        #pragma unroll
        for (int mi = 0; mi < 4; ++mi)
            #pragma unroll
            for (int ni = 0; ni < 4; ++ni)
                #pragma unroll
                for (int kc = 0; kc < 2; ++kc)
                    acc[mi][ni] = mfma_bf16(af[mi][kc], bfv[ni][kc], acc[mi][ni]);
        __syncthreads();
    }

    #pragma unroll
    for (int ni = 0; ni < 4; ++ni) {
        int colr = nt0 + wn + ni * 16 + li;
        if (colr < nsz) {
            float bv = bias[colr];
            #pragma unroll
            for (int mi = 0; mi < 4; ++mi)
                #pragma unroll
                for (int r = 0; r < 4; ++r) {
                    int row = m0 + wm + mi * 16 + lg * 4 + r;
                    C[(size_t)row * ldc + cb + colr] = acc[mi][ni][r] + bv;
                }
        }
    }
}

// ---------------------------------------------------------------------------
// RoPE + bf16 convert. qkv fp32 [1024][5120] -> q(scaled by 0.125) [1024][4096],
// k [1024][512], v [1024][512], all bf16.
// ---------------------------------------------------------------------------
__global__ void rope_kernel(const float* __restrict__ qkv,
                            u16* __restrict__ qo, u16* __restrict__ ko, u16* __restrict__ vo)
{
    int id = blockIdx.x * 256 + threadIdx.x;   // 1024 * 2560
    int s  = id / 2560;
    int r  = id % 2560;
    const float* row = qkv + (size_t)s * 5120;
    if (r < 2304) {
        bool isq = r < 2048;
        int rr   = isq ? r : r - 2048;
        int hh   = rr >> 5;
        int d    = rr & 31;
        int col  = (isq ? 0 : 4096) + hh * 64 + d;
        float t1 = row[col], t2 = row[col + 32];
        // inv_freq = 150000^(-d/32) = exp2(-d * log2(150000)/32)
        float ang = (float)s * exp2f((float)d * -0.5373314f);
        float sn, cs;
        sincosf(ang, &sn, &cs);
        float sc = isq ? 0.125f : 1.0f;    // fold score scale HD^-0.5 into q
        float o1 = (t1 * cs - t2 * sn) * sc;
        float o2 = (t1 * sn + t2 * cs) * sc;
        u16* dst = isq ? qo : ko;
        int ldd  = isq ? 4096 : 512;
        int dcol = isq ? col : col - 4096;
        dst[(size_t)s * ldd + dcol]      = f2bf(o1);
        dst[(size_t)s * ldd + dcol + 32] = f2bf(o2);
    } else {
        int e = (r - 2304) * 2;
        vo[(size_t)s * 512 + e]     = f2bf(row[4608 + e]);
        vo[(size_t)s * 512 + e + 1] = f2bf(row[4608 + e + 1]);
    }
}

// ---------------------------------------------------------------------------
// Sliding-window GQA attention with sinks. Block = (head, 64-query block),
// 4 waves x 16 queries. K staged via gload_lds+swizzle, online softmax with
// m0=sink,l0=1, P via per-wave LDS roundtrip, V fragments direct from global.
// Writes bf16 att-out [1024][64*64].
// ---------------------------------------------------------------------------
__global__ __launch_bounds__(256, 2) void attn_kernel(
    const u16* __restrict__ Q, const u16* __restrict__ Kb, const u16* __restrict__ Vb,
    const float* __restrict__ sinks, u16* __restrict__ Ob)
{
    __shared__ u16 Kls[64 * 64];
    __shared__ u16 Pls[4][16 * 72];

    const int h    = blockIdx.x;
    const int qblk = blockIdx.y;
    const int kvh  = h >> 3;
    const int tid  = threadIdx.x;
    const int lane = tid & 63;
    const int w    = tid >> 6;
    const int li   = lane & 15;
    const int lg   = lane >> 4;
    const int qw   = qblk * 64 + w * 16;

    s16x8 aq[2];
    {
        const u16* qrow = Q + ((size_t)(qw + li) * 64 + h) * 64 + lg * 8;
        aq[0] = *(const s16x8*)(qrow);
        aq[1] = *(const s16x8*)(qrow + 32);
    }

    const float snk = sinks[h];
    float m_run[4], l_run[4];
    f32x4 oacc[4];
    #pragma unroll
    for (int r = 0; r < 4; ++r) { m_run[r] = snk; l_run[r] = 1.0f; }
    #pragma unroll
    for (int ni = 0; ni < 4; ++ni) oacc[ni] = (f32x4){0.f, 0.f, 0.f, 0.f};

    const int srow = tid >> 3;
    const int slc  = (tid & 7) ^ (srow & 7);

    for (int t = 0; t < 3; ++t) {
        int jt = qblk - 2 + t;
        if (jt < 0) continue;
        int j0 = jt * 64;

        #pragma unroll
        for (int it = 0; it < 2; ++it) {
            const u16* src = Kb + ((size_t)(j0 + it * 32 + srow) * 8 + kvh) * 64 + slc * 8;
            GLOAD16(src, Kls + (it * 256 + w * 64) * 8);
        }
        __syncthreads();

        f32x4 sc[4];
        #pragma unroll
        for (int nf = 0; nf < 4; ++nf) {
            sc[nf] = (f32x4){0.f, 0.f, 0.f, 0.f};
            #pragma unroll
            for (int kc = 0; kc < 2; ++kc) {
                int row = nf * 16 + li;
                int ch  = (kc * 4 + lg) ^ (row & 7);
                s16x8 bk = *(const s16x8*)&Kls[row * 64 + ch * 8];
                sc[nf] = mfma_bf16(aq[kc], bk, sc[nf]);
            }
        }

        #pragma unroll
        for (int r = 0; r < 4; ++r) {
            const int qg = qw + lg * 4 + r;
            float mx = -1e30f;
            #pragma unroll
            for (int nf = 0; nf < 4; ++nf) {
                int jg = j0 + nf * 16 + li;
                bool ok = (jg <= qg) && (qg - jg < 128);
                float v = ok ? sc[nf][r] : -1e30f;
                sc[nf][r] = v;
                mx = fmaxf(mx, v);
            }
            #pragma unroll
            for (int off = 1; off < 16; off <<= 1)
                mx = fmaxf(mx, __shfl_xor(mx, off));
            float mnew = fmaxf(m_run[r], mx);
            float corr = __expf(m_run[r] - mnew);
            m_run[r] = mnew;
            float rs = 0.f;
            #pragma unroll
            for (int nf = 0; nf < 4; ++nf) {
                float p = __expf(sc[nf][r] - mnew);
                rs += p;
                Pls[w][(lg * 4 + r) * 72 + nf * 16 + li] = f2bf(p);
            }
            #pragma unroll
            for (int off = 1; off < 16; off <<= 1)
                rs += __shfl_xor(rs, off);
            l_run[r] = l_run[r] * corr + rs;
            #pragma unroll
            for (int ni = 0; ni < 4; ++ni) oacc[ni][r] *= corr;
        }
        __syncthreads();   // all K reads done; P writes drained

        #pragma unroll
        for (int kc = 0; kc < 2; ++kc) {
            s16x8 pa = *(const s16x8*)&Pls[w][li * 72 + kc * 32 + lg * 8];
            #pragma unroll
            for (int ni = 0; ni < 4; ++ni) {
                const u16* vsrc = Vb + ((size_t)(j0 + kc * 32 + lg * 8) * 8 + kvh) * 64 + ni * 16 + li;
                s16x8 bv;
                #pragma unroll
                for (int i = 0; i < 8; ++i) bv[i] = (short)vsrc[(size_t)i * 512];
                oacc[ni] = mfma_bf16(pa, bv, oacc[ni]);
            }
        }
    }

    #pragma unroll
    for (int r = 0; r < 4; ++r) {
        float inv = 1.0f / l_run[r];
        #pragma unroll
        for (int ni = 0; ni < 4; ++ni)
            Ob[((size_t)(qw + lg * 4 + r) * 64 + h) * 64 + ni * 16 + li] = f2bf(oacc[ni][r] * inv);
    }
}

// ---------------------------------------------------------------------------
extern "C" void kernel_launch(void* const* d_in, const int* in_sizes, int n_in,
                              void* d_out, int out_size, void* d_ws, size_t ws_size,
                              hipStream_t stream)
{
    const float* x     = (const float*)d_in[0];
    const float* wq_w  = (const float*)d_in[1];
    const float* wq_b  = (const float*)d_in[2];
    const float* wk_w  = (const float*)d_in[3];
    const float* wk_b  = (const float*)d_in[4];
    const float* wv_w  = (const float*)d_in[5];
    const float* wv_b  = (const float*)d_in[6];
    const float* wo_w  = (const float*)d_in[7];
    const float* wo_b  = (const float*)d_in[8];
    const float* sinks = (const float*)d_in[9];

    char* ws = (char*)d_ws;
    float* qkv  = (float*)(ws + 0);              // 20,971,520 B (fp32 [1024][5120])
    u16*   attb = (u16*)  (ws + 0);              // overlay: attn out bf16 (qkv dead by then)
    u16*   xb   = (u16*)  (ws + 20971520ULL);
    u16*   wqb  = (u16*)  (ws + 26869760ULL);
    u16*   wkb  = (u16*)  (ws + 50462720ULL);
    u16*   wvb  = (u16*)  (ws + 53411840ULL);
    u16*   wob  = (u16*)  (ws + 56360960ULL);
    u16*   qr   = (u16*)  (ws + 79953920ULL);
    u16*   kr   = (u16*)  (ws + 88342528ULL);
    u16*   vbf  = (u16*)  (ws + 89391104ULL);    // end: 90,439,680 B

    (void)in_sizes; (void)n_in; (void)out_size; (void)ws_size;

    // 1) bf16 conversions
    cvt_all_kernel<<<28800, 256, 0, stream>>>(x, wq_w, wk_w, wv_w, wo_w,
                                              xb, wqb, wkb, wvb, wob);
    // 2) fused QKV projection -> qkv fp32 [1024][5120]
    gemm_bf16nt<<<dim3(40, 8), 256, 0, stream>>>(xb, 2880, 2880,
        wqb, wq_b, 32, 4096, 0,
        wkb, wk_b, 4, 512, 4096,
        wvb, wv_b, 4, 512, 4608,
        qkv, 5120);
    // 3) RoPE + convert (q pre-scaled by 0.125)
    rope_kernel<<<10240, 256, 0, stream>>>(qkv, qr, kr, vbf);
    // 4) attention -> attb bf16 [1024][4096]
    attn_kernel<<<dim3(64, 16), 256, 0, stream>>>(qr, kr, vbf, sinks, attb);
    // 5) output projection -> d_out fp32 [1024][2880]
    gemm_bf16nt<<<dim3(23, 8), 256, 0, stream>>>(attb, 4096, 4096,
        wob, wo_b, 23, 2880, 0,
        wob, wo_b, 0, 0, 0,
        wob, wo_b, 0, 0, 0,
        (float*)d_out, 2880);
}

// Round 2
// 169.144 us; speedup vs baseline: 1.0323x; 1.0323x over previous
//
#include <hip/hip_runtime.h>

typedef __attribute__((ext_vector_type(4))) float f32x4;
typedef __attribute__((ext_vector_type(8))) short s16x8;
typedef unsigned short u16;

#define DEVI __device__ __forceinline__

// fp32 -> bf16 round-to-nearest-even
DEVI u16 f2bf(float f) {
    union { float f; unsigned int u; } v; v.f = f;
    unsigned int r = v.u + 0x7FFFu + ((v.u >> 16) & 1u);
    return (u16)(r >> 16);
}

typedef __attribute__((address_space(1))) void gv_t;   // global
typedef __attribute__((address_space(3))) void sv_t;   // LDS

#define GLOAD16(SRC, DST) __builtin_amdgcn_global_load_lds( \
    (gv_t*)(SRC), (sv_t*)(DST), 16, 0, 0)

DEVI f32x4 mfma_bf16(s16x8 a, s16x8 b, f32x4 c) {
    return __builtin_amdgcn_mfma_f32_16x16x32_bf16(a, b, c, 0, 0, 0);
}

// ---------------------------------------------------------------------------
// fp32 -> bf16 conversion of x, wq, wk, wv, wo (one fused streaming pass)
// ---------------------------------------------------------------------------
__global__ void cvt_all_kernel(
    const float* __restrict__ x,  const float* __restrict__ wq, const float* __restrict__ wk,
    const float* __restrict__ wv, const float* __restrict__ wo,
    u16* __restrict__ xb, u16* __restrict__ wqb, u16* __restrict__ wkb,
    u16* __restrict__ wvb, u16* __restrict__ wob)
{
    int id = blockIdx.x * 256 + threadIdx.x;   // 0 .. 7372800-1
    const float* s; u16* d; int off;
    if      (id < 737280)  { s = x;  d = xb;  off = id; }
    else if (id < 3686400) { s = wq; d = wqb; off = id - 737280; }
    else if (id < 4055040) { s = wk; d = wkb; off = id - 3686400; }
    else if (id < 4423680) { s = wv; d = wvb; off = id - 4055040; }
    else                   { s = wo; d = wob; off = id - 4423680; }
    f32x4 v = *(const f32x4*)(s + (size_t)off * 4);
    union { u16 u[4]; unsigned long long ll; } o;
    #pragma unroll
    for (int j = 0; j < 4; ++j) o.u[j] = f2bf(v[j]);
    *(unsigned long long*)(d + (size_t)off * 4) = o.ll;
}

// ---------------------------------------------------------------------------
// NT GEMM, split-K, 2-phase pipelined (T3-min):
// C_part[z] = A[M][K] * W[n][K]^T  (bf16 in, fp32 partial out, NO bias).
// 128x128 tile, BK=64, 4 waves of 64x64, 16x16x32 MFMA.
// Double-buffered LDS; next tile's global_load_lds issued before current
// tile's compute; single __syncthreads per iter (drains vmcnt after MFMA).
// ---------------------------------------------------------------------------
__global__ __launch_bounds__(256, 2) void gemm_bf16nt(
    const u16* __restrict__ A, int lda, int kit,
    const u16* __restrict__ W0, int t0, int n0, int c0,
    const u16* __restrict__ W1, int t1, int n1, int c1,
    const u16* __restrict__ W2, int t2, int n2, int c2,
    float* __restrict__ C, int ldc, long long cstride)
{
    __shared__ u16 Als[2][128 * 64];
    __shared__ u16 Bls[2][128 * 64];

    const int tid  = threadIdx.x;
    const int lane = tid & 63;
    const int wid  = tid >> 6;
    const int li   = lane & 15;
    const int lg   = lane >> 4;
    const int m0   = blockIdx.y * 128;

    const u16* W; int nt0, nsz;
    int cb;
    {
        int nb = blockIdx.x;
        if (nb < t0)           { W = W0; nt0 = nb * 128;             nsz = n0; cb = c0; }
        else if (nb < t0 + t1) { W = W1; nt0 = (nb - t0) * 128;      nsz = n1; cb = c1; }
        else                   { W = W2; nt0 = (nb - t0 - t1) * 128; nsz = n2; cb = c2; }
    }

    // K-split range (in units of 64-wide iterations)
    const int z  = blockIdx.z;
    const int S  = gridDim.z;
    const int it0 = (z * kit) / S;
    const int it1 = ((z + 1) * kit) / S;
    float* Cp = C + (long long)z * cstride;

    const int wm = (wid >> 1) * 64;
    const int wn = (wid & 1) * 64;

    f32x4 acc[4][4];
    #pragma unroll
    for (int mi = 0; mi < 4; ++mi)
        #pragma unroll
        for (int ni = 0; ni < 4; ++ni)
            acc[mi][ni] = (f32x4){0.f, 0.f, 0.f, 0.f};

    const int srow = tid >> 3;                 // 0..31
    const int slc  = (tid & 7) ^ (srow & 7);   // inverse-swizzled source chunk

    // ---- staging helper (as lambda-ish macros) ----
#define STAGE(BUF, IT)                                                          \
    do {                                                                        \
        int k0_ = (IT) * 64;                                                    \
        _Pragma("unroll")                                                       \
        for (int s_ = 0; s_ < 4; ++s_) {                                        \
            const u16* sa_ = A + (size_t)(m0 + s_ * 32 + srow) * lda + k0_ + slc * 8; \
            GLOAD16(sa_, &Als[BUF][(s_ * 256 + wid * 64) * 8]);                 \
        }                                                                       \
        _Pragma("unroll")                                                       \
        for (int s_ = 0; s_ < 4; ++s_) {                                        \
            int wr_ = nt0 + s_ * 32 + srow;                                     \
            if (wr_ > nsz - 1) wr_ = nsz - 1;                                   \
            const u16* sb_ = W + (size_t)wr_ * lda + k0_ + slc * 8;             \
            GLOAD16(sb_, &Bls[BUF][(s_ * 256 + wid * 64) * 8]);                 \
        }                                                                       \
    } while (0)

    STAGE(0, it0);
    __syncthreads();
    int cur = 0;

    for (int it = it0; it < it1; ++it) {
        if (it + 1 < it1) STAGE(cur ^ 1, it + 1);

        s16x8 af[4][2], bfv[4][2];
        #pragma unroll
        for (int mi = 0; mi < 4; ++mi)
            #pragma unroll
            for (int kc = 0; kc < 2; ++kc) {
                int row = wm + mi * 16 + li;
                int ch  = (kc * 4 + lg) ^ (row & 7);
                af[mi][kc] = *(const s16x8*)&Als[cur][row * 64 + ch * 8];
            }
        #pragma unroll
        for (int ni = 0; ni < 4; ++ni)
            #pragma unroll
            for (int kc = 0; kc < 2; ++kc) {
                int row = wn + ni * 16 + li;
                int ch  = (kc * 4 + lg) ^ (row & 7);
                bfv[ni][kc] = *(const s16x8*)&Bls[cur][row * 64 + ch * 8];
            }
        #pragma unroll
        for (int mi = 0; mi < 4; ++mi)
            #pragma unroll
            for (int ni = 0; ni < 4; ++ni)
                #pragma unroll
                for (int kc = 0; kc < 2; ++kc)
                    acc[mi][ni] = mfma_bf16(af[mi][kc], bfv[ni][kc], acc[mi][ni]);

        __syncthreads();   // drains next tile's gload_lds + protects buffers
        cur ^= 1;
    }
#undef STAGE

    #pragma unroll
    for (int ni = 0; ni < 4; ++ni) {
        int colr = nt0 + wn + ni * 16 + li;
        if (colr < nsz) {
            #pragma unroll
            for (int mi = 0; mi < 4; ++mi)
                #pragma unroll
                for (int r = 0; r < 4; ++r) {
                    int row = m0 + wm + mi * 16 + lg * 4 + r;
                    Cp[(size_t)row * ldc + cb + colr] = acc[mi][ni][r];
                }
        }
    }
}

// ---------------------------------------------------------------------------
// RoPE + bias + bf16 convert from 2 split-K partials.
// qkv = p0 + p1 + bias; q scaled by 0.125; outputs bf16.
// ---------------------------------------------------------------------------
__global__ void rope_kernel(const float* __restrict__ p0, const float* __restrict__ p1,
                            const float* __restrict__ qb, const float* __restrict__ kb,
                            const float* __restrict__ vb,
                            u16* __restrict__ qo, u16* __restrict__ ko, u16* __restrict__ vo)
{
    int id = blockIdx.x * 256 + threadIdx.x;   // 1024 * 2560
    int s  = id / 2560;
    int r  = id % 2560;
    const float* r0 = p0 + (size_t)s * 5120;
    const float* r1 = p1 + (size_t)s * 5120;
    if (r < 2304) {
        bool isq = r < 2048;
        int rr   = isq ? r : r - 2048;
        int hh   = rr >> 5;
        int d    = rr & 31;
        int col  = (isq ? 0 : 4096) + hh * 64 + d;
        int bcol = isq ? col : col - 4096;
        const float* bias = isq ? qb : kb;
        float t1 = r0[col]      + r1[col]      + bias[bcol];
        float t2 = r0[col + 32] + r1[col + 32] + bias[bcol + 32];
        // inv_freq = 150000^(-d/32) = exp2(-d * log2(150000)/32)
        float ang = (float)s * exp2f((float)d * -0.5373314f);
        float sn, cs;
        sincosf(ang, &sn, &cs);
        float sc = isq ? 0.125f : 1.0f;    // fold score scale HD^-0.5 into q
        float o1 = (t1 * cs - t2 * sn) * sc;
        float o2 = (t1 * sn + t2 * cs) * sc;
        u16* dst = isq ? qo : ko;
        int ldd  = isq ? 4096 : 512;
        dst[(size_t)s * ldd + bcol]      = f2bf(o1);
        dst[(size_t)s * ldd + bcol + 32] = f2bf(o2);
    } else {
        int e = (r - 2304) * 2;
        int c0 = 4608 + e;
        vo[(size_t)s * 512 + e]     = f2bf(r0[c0]     + r1[c0]     + vb[e]);
        vo[(size_t)s * 512 + e + 1] = f2bf(r0[c0 + 1] + r1[c0 + 1] + vb[e + 1]);
    }
}

// ---------------------------------------------------------------------------
// out = sum of 4 split-K partials + bias (fp32)
// ---------------------------------------------------------------------------
__global__ void reduce_out_kernel(const float* __restrict__ parts,
                                  const float* __restrict__ bias,
                                  float* __restrict__ out)
{
    int id = blockIdx.x * 256 + threadIdx.x;      // f32x4 index, 0..737279
    const long long stride = 1024LL * 2880 / 4;   // in f32x4 units
    f32x4 s = ((const f32x4*)parts)[id];
    s += ((const f32x4*)parts)[id + stride];
    s += ((const f32x4*)parts)[id + 2 * stride];
    s += ((const f32x4*)parts)[id + 3 * stride];
    int cb = (id % 720) * 4;
    f32x4 b = *(const f32x4*)(bias + cb);
    ((f32x4*)out)[id] = s + b;
}

// ---------------------------------------------------------------------------
// Sliding-window GQA attention with sinks (unchanged from R1).
// ---------------------------------------------------------------------------
__global__ __launch_bounds__(256, 2) void attn_kernel(
    const u16* __restrict__ Q, const u16* __restrict__ Kb, const u16* __restrict__ Vb,
    const float* __restrict__ sinks, u16* __restrict__ Ob)
{
    __shared__ u16 Kls[64 * 64];
    __shared__ u16 Pls[4][16 * 72];

    const int h    = blockIdx.x;
    const int qblk = blockIdx.y;
    const int kvh  = h >> 3;
    const int tid  = threadIdx.x;
    const int lane = tid & 63;
    const int w    = tid >> 6;
    const int li   = lane & 15;
    const int lg   = lane >> 4;
    const int qw   = qblk * 64 + w * 16;

    s16x8 aq[2];
    {
        const u16* qrow = Q + ((size_t)(qw + li) * 64 + h) * 64 + lg * 8;
        aq[0] = *(const s16x8*)(qrow);
        aq[1] = *(const s16x8*)(qrow + 32);
    }

    const float snk = sinks[h];
    float m_run[4], l_run[4];
    f32x4 oacc[4];
    #pragma unroll
    for (int r = 0; r < 4; ++r) { m_run[r] = snk; l_run[r] = 1.0f; }
    #pragma unroll
    for (int ni = 0; ni < 4; ++ni) oacc[ni] = (f32x4){0.f, 0.f, 0.f, 0.f};

    const int srow = tid >> 3;
    const int slc  = (tid & 7) ^ (srow & 7);

    for (int t = 0; t < 3; ++t) {
        int jt = qblk - 2 + t;
        if (jt < 0) continue;
        int j0 = jt * 64;

        #pragma unroll
        for (int it = 0; it < 2; ++it) {
            const u16* src = Kb + ((size_t)(j0 + it * 32 + srow) * 8 + kvh) * 64 + slc * 8;
            GLOAD16(src, &Kls[(it * 256 + w * 64) * 8]);
        }
        __syncthreads();

        f32x4 sc[4];
        #pragma unroll
        for (int nf = 0; nf < 4; ++nf) {
            sc[nf] = (f32x4){0.f, 0.f, 0.f, 0.f};
            #pragma unroll
            for (int kc = 0; kc < 2; ++kc) {
                int row = nf * 16 + li;
                int ch  = (kc * 4 + lg) ^ (row & 7);
                s16x8 bk = *(const s16x8*)&Kls[row * 64 + ch * 8];
                sc[nf] = mfma_bf16(aq[kc], bk, sc[nf]);
            }
        }

        #pragma unroll
        for (int r = 0; r < 4; ++r) {
            const int qg = qw + lg * 4 + r;
            float mx = -1e30f;
            #pragma unroll
            for (int nf = 0; nf < 4; ++nf) {
                int jg = j0 + nf * 16 + li;
                bool ok = (jg <= qg) && (qg - jg < 128);
                float v = ok ? sc[nf][r] : -1e30f;
                sc[nf][r] = v;
                mx = fmaxf(mx, v);
            }
            #pragma unroll
            for (int off = 1; off < 16; off <<= 1)
                mx = fmaxf(mx, __shfl_xor(mx, off));
            float mnew = fmaxf(m_run[r], mx);
            float corr = __expf(m_run[r] - mnew);
            m_run[r] = mnew;
            float rs = 0.f;
            #pragma unroll
            for (int nf = 0; nf < 4; ++nf) {
                float p = __expf(sc[nf][r] - mnew);
                rs += p;
                Pls[w][(lg * 4 + r) * 72 + nf * 16 + li] = f2bf(p);
            }
            #pragma unroll
            for (int off = 1; off < 16; off <<= 1)
                rs += __shfl_xor(rs, off);
            l_run[r] = l_run[r] * corr + rs;
            #pragma unroll
            for (int ni = 0; ni < 4; ++ni) oacc[ni][r] *= corr;
        }
        __syncthreads();   // all K reads done; P writes drained

        #pragma unroll
        for (int kc = 0; kc < 2; ++kc) {
            s16x8 pa = *(const s16x8*)&Pls[w][li * 72 + kc * 32 + lg * 8];
            #pragma unroll
            for (int ni = 0; ni < 4; ++ni) {
                const u16* vsrc = Vb + ((size_t)(j0 + kc * 32 + lg * 8) * 8 + kvh) * 64 + ni * 16 + li;
                s16x8 bv;
                #pragma unroll
                for (int i = 0; i < 8; ++i) bv[i] = (short)vsrc[(size_t)i * 512];
                oacc[ni] = mfma_bf16(pa, bv, oacc[ni]);
            }
        }
    }

    #pragma unroll
    for (int r = 0; r < 4; ++r) {
        float inv = 1.0f / l_run[r];
        #pragma unroll
        for (int ni = 0; ni < 4; ++ni)
            Ob[((size_t)(qw + lg * 4 + r) * 64 + h) * 64 + ni * 16 + li] = f2bf(oacc[ni][r] * inv);
    }
}

// ---------------------------------------------------------------------------
extern "C" void kernel_launch(void* const* d_in, const int* in_sizes, int n_in,
                              void* d_out, int out_size, void* d_ws, size_t ws_size,
                              hipStream_t stream)
{
    const float* x     = (const float*)d_in[0];
    const float* wq_w  = (const float*)d_in[1];
    const float* wq_b  = (const float*)d_in[2];
    const float* wk_w  = (const float*)d_in[3];
    const float* wk_b  = (const float*)d_in[4];
    const float* wv_w  = (const float*)d_in[5];
    const float* wv_b  = (const float*)d_in[6];
    const float* wo_w  = (const float*)d_in[7];
    const float* wo_b  = (const float*)d_in[8];
    const float* sinks = (const float*)d_in[9];

    char* ws = (char*)d_ws;
    // layout (bytes):
    //   [0, 35,389,440)           xb | wqb | wkb | wvb          (cvt -> gemm1)
    //   [35,389,440, 77,332,480)  qkv partials (2 x 20,971,520) (gemm1 -> rope)
    //   [77,332,480, 87,818,240)  qr | kr | vbf                 (rope -> attn)
    //   [87,818,240, 96,206,848)  attb                          (attn -> gemm2)
    //   [96,206,848, 119,799,808) wob                           (cvt -> gemm2)
    //   out_parts (4 x 11,796,480 = 47,185,920) overlays [0, 47,185,920)
    //     (xb/wqb/wkb/wvb + qkv partials are dead by gemm2)
    u16*   xb   = (u16*)  (ws + 0);
    u16*   wqb  = (u16*)  (ws + 5898240ULL);
    u16*   wkb  = (u16*)  (ws + 29491200ULL);
    u16*   wvb  = (u16*)  (ws + 32440320ULL);
    float* qkvp = (float*)(ws + 35389440ULL);      // 2 partials, stride 1024*5120
    u16*   qr   = (u16*)  (ws + 77332480ULL);
    u16*   kr   = (u16*)  (ws + 85721088ULL);
    u16*   vbf  = (u16*)  (ws + 86769664ULL);
    u16*   attb = (u16*)  (ws + 87818240ULL);
    u16*   wob  = (u16*)  (ws + 96206848ULL);
    float* oprt = (float*)(ws + 0);                // 4 partials, stride 1024*2880

    (void)in_sizes; (void)n_in; (void)out_size; (void)ws_size;

    // 1) bf16 conversions
    cvt_all_kernel<<<28800, 256, 0, stream>>>(x, wq_w, wk_w, wv_w, wo_w,
                                              xb, wqb, wkb, wvb, wob);
    // 2) fused QKV projection, split-K=2 -> 2 fp32 partials [1024][5120]
    gemm_bf16nt<<<dim3(40, 8, 2), 256, 0, stream>>>(xb, 2880, 45,
        wqb, 32, 4096, 0,
        wkb, 4, 512, 4096,
        wvb, 4, 512, 4608,
        qkvp, 5120, 1024LL * 5120);
    // 3) RoPE + partial-sum + bias + convert (q pre-scaled by 0.125)
    rope_kernel<<<10240, 256, 0, stream>>>(qkvp, qkvp + 1024LL * 5120,
                                           wq_b, wk_b, wv_b, qr, kr, vbf);
    // 4) attention -> attb bf16 [1024][4096]
    attn_kernel<<<dim3(64, 16), 256, 0, stream>>>(qr, kr, vbf, sinks, attb);
    // 5) output projection, split-K=4 -> 4 fp32 partials [1024][2880]
    gemm_bf16nt<<<dim3(23, 8, 4), 256, 0, stream>>>(attb, 4096, 64,
        wob, 23, 2880, 0,
        wob, 0, 0, 0,
        wob, 0, 0, 0,
        oprt, 2880, 1024LL * 2880);
    // 6) reduce partials + bias -> d_out fp32 [1024][2880]
    reduce_out_kernel<<<2880, 256, 0, stream>>>(oprt, wo_b, (float*)d_out);
}